// Round 5
// baseline (85.657 us; speedup 1.0000x reference)
//
#include <hip/hip_runtime.h>
#include <math.h>

#define K_SIZE 5
#define EPS    1e-6f
#define EPS_L  1e-3f
#define EPS_W  1e-3f

#define BATCH 4
#define HGT   512
#define WID   512
#define HW    (HGT * WID)

typedef int int32x4 __attribute__((ext_vector_type(4)));

// Raw buffer load with hardware bounds check: OOB -> returns 0.0f
__device__ float llvm_amdgcn_raw_buffer_load_fp32(int32x4 srsrc, int voffset,
                                                  int soffset, int aux)
    __asm("llvm.amdgcn.raw.buffer.load.f32");

__global__ __launch_bounds__(256, 4) void fused_sample_kernel(
    const float* __restrict__ input,   // (B,1,H,W)
    const float* __restrict__ Lp,      // (B,H,W,3)
    const float* __restrict__ wbuf,    // (B,2,H,W)
    float* __restrict__ out)           // (B,1,H,W)
{
#pragma clang fp contract(off)
    // ---- 2D tiled mapping: block = 16x16 pixel tile, wave = 8x8 sub-tile ----
    // blockIdx: [b(2b) | tileY(5b) | tileX(5b)]
    const int b     = blockIdx.x >> 10;
    const int tileY = (blockIdx.x >> 5) & 31;
    const int tileX = blockIdx.x & 31;

    const int lane = threadIdx.x & 63;
    const int wv   = threadIdx.x >> 6;       // 0..3 -> 2x2 quadrants of 8x8
    const int lx   = lane & 7;
    const int ly   = lane >> 3;

    const int x = (tileX << 4) + ((wv & 1) << 3) + lx;
    const int y = (tileY << 4) + ((wv >> 1) << 3) + ly;
    const int p = (y << 9) + x;
    const int idx = b * HW + p;

    // SRD for this batch's image: OOB rows fall outside num_records -> 0.
    union {
        struct { const void* base; unsigned num; unsigned cfg; } s;
        int32x4 v;
    } desc;
    desc.s.base = (const void*)(input + (size_t)b * HW);
    desc.s.num  = HW * 4u;
    desc.s.cfg  = 0x00020000u;
    const int32x4 rsrc = desc.v;

    // ---- per-pixel matrix (exactly mirrors numpy op order; amplified path) ----
    const size_t l_off = (size_t)idx * 3;
    const float L0 = Lp[l_off + 0];
    const float L1 = Lp[l_off + 1];
    const float L2 = Lp[l_off + 2];

    const float a  = fabsf(L0) + EPS_L;
    const float bb = L1;
    const float c  = fabsf(L2) + EPS_L;

    const float M00 = a * a;
    const float M01 = a * bb;
    const float M11 = (bb * bb) + (c * c);

    const float d00 = M00 + EPS;
    const float d11 = M11 + EPS;
    const float det = (d00 * d11) - (M01 * M01);
    const float I00 = d11 / det;          // IEEE f32 div, same as np
    const float I01 = (-M01) / det;
    const float I11 = d00 / det;

    const float wx = wbuf[(size_t)b * 2 * HW + p];
    const float wy = wbuf[(size_t)b * 2 * HW + HW + p];

    const float q    = (((I00 * wx) * wx) + (((2.0f * I01) * wx) * wy)) + ((I11 * wy) * wy);
    const float norm = sqrtf(q + EPS);

    const float e    = (float)exp((double)(-norm));   // correctly-rounded f32 exp
    const float sig  = 1.0f / (1.0f + e);
    const float tuned = ((sig - 0.5f) * 2.0f) * (1.0f - EPS_W);
    const float scale = tuned / (norm + EPS);         // IEEE div
    const float wtx = wx * scale;
    const float wty = wy * scale;

    // cos/sin of the FLOAT32-ROUNDED theta_k
    const float CT[K_SIZE] = { 1.0f,  0.30901696090f, -0.80901703575f, -0.80901693229f,  0.30901712828f };
    const float ST[K_SIZE] = { 0.0f,  0.95105652717f,  0.58778519534f, -0.58778533774f, -0.95105647279f };
    const float SV[K_SIZE] = { 0.2f, 0.4f, 0.6f, 0.8f, 1.0f };

    const float fy = (float)y;
    const float fx = (float)x;

    float acc0 = 0.0f;
    float acc1 = 0.0f;

    #pragma unroll
    for (int k = 0; k < K_SIZE; ++k) {
        const float ct = CT[k];
        const float st = ST[k];
        // amplified path: keep exact left-assoc, no contraction
        const float quad = (((M00 * ct) * ct) + (((2.0f * M01) * ct) * st)) + ((M11 * st) * st);
        const float F    = (sqrtf(quad) + (wtx * ct)) + (wty * st);
        const float Fe   = F + EPS;
        // downstream of cancellation: approx rcp safe (position error ~1e-7 rel)
        const float rFe  = __builtin_amdgcn_rcpf(Fe);
        const float yx   = ct * rFe;
        const float yy   = st * rFe;

        #pragma unroll
        for (int s = 0; s < K_SIZE; ++s) {
            const float sv = SV[s];
            const float gy = fmaf(sv, yy, fy);
            const float gx = fmaf(sv, yx, fx);

            const int   y0i = (int)floorf(gy);      // v_cvt_flr_i32_f32 (saturating)
            const int   x0i = (int)floorf(gx);
            const float wyf = __builtin_amdgcn_fractf(gy);
            const float wxf = __builtin_amdgcn_fractf(gx);

            // y handled by HW bounds check: OOB row -> address outside SRD -> 0.
            const unsigned r0 = (unsigned)y0i << 11;          // byte offset of row y0
            const unsigned r1 = r0 + (WID * 4u);              // row y0+1

            // x must be clamped (x wrap would alias a neighboring row)
            const int x1i = x0i + 1;
            const bool vx0 = (unsigned)x0i < (unsigned)WID;
            const bool vx1 = (unsigned)x1i < (unsigned)WID;
            const unsigned x0v = (unsigned)min(max(x0i, 0), WID - 1) << 2;
            const unsigned x1v = (unsigned)min(max(x1i, 0), WID - 1) << 2;

            const float v00 = llvm_amdgcn_raw_buffer_load_fp32(rsrc, (int)(r0 + x0v), 0, 0);
            const float v01 = llvm_amdgcn_raw_buffer_load_fp32(rsrc, (int)(r0 + x1v), 0, 0);
            const float v10 = llvm_amdgcn_raw_buffer_load_fp32(rsrc, (int)(r1 + x0v), 0, 0);
            const float v11 = llvm_amdgcn_raw_buffer_load_fp32(rsrc, (int)(r1 + x1v), 0, 0);

            const float zx0 = vx0 ? (1.0f - wxf) : 0.0f;
            const float zx1 = vx1 ? wxf : 0.0f;

            const float row0 = fmaf(v01, zx1, v00 * zx0);
            const float row1 = fmaf(v11, zx1, v10 * zx0);

            if (s & 1) {
                acc1 = fmaf(1.0f - wyf, row0, acc1);
                acc1 = fmaf(wyf,        row1, acc1);
            } else {
                acc0 = fmaf(1.0f - wyf, row0, acc0);
                acc0 = fmaf(wyf,        row1, acc0);
            }
        }
    }

    out[idx] = (acc0 + acc1) / (float)(K_SIZE * K_SIZE);
}

extern "C" void kernel_launch(void* const* d_in, const int* in_sizes, int n_in,
                              void* d_out, int out_size, void* d_ws, size_t ws_size,
                              hipStream_t stream) {
    const float* input = (const float*)d_in[0];
    const float* Lp    = (const float*)d_in[1];
    const float* wbuf  = (const float*)d_in[2];
    float* out = (float*)d_out;

    const int grid = BATCH * 32 * 32;        // 4096 blocks, 16x16 px each
    fused_sample_kernel<<<grid, 256, 0, stream>>>(input, Lp, wbuf, out);
}

// Round 6
// 55.315 us; speedup vs baseline: 1.5485x; 1.5485x over previous
//
#include <hip/hip_runtime.h>
#include <math.h>

#define K_SIZE 5
#define EPS    1e-6f
#define EPS_L  1e-3f
#define EPS_W  1e-3f

#define BATCH 4
#define HGT   512
#define WID   512
#define HW    (HGT * WID)

typedef int int32x4 __attribute__((ext_vector_type(4)));

// Raw buffer load with hardware bounds check: OOB -> returns 0.0f
__device__ float llvm_amdgcn_raw_buffer_load_fp32(int32x4 srsrc, int voffset,
                                                  int soffset, int aux)
    __asm("llvm.amdgcn.raw.buffer.load.f32");

__global__ __launch_bounds__(256) void fused_sample_kernel(
    const float* __restrict__ input,   // (B,1,H,W)
    const float* __restrict__ Lp,      // (B,H,W,3)
    const float* __restrict__ wbuf,    // (B,2,H,W)
    float* __restrict__ out)           // (B,1,H,W)
{
#pragma clang fp contract(off)
    // Linear mapping: contiguous idx across lanes (coalesced Lp/w/out).
    const int idx = blockIdx.x * blockDim.x + threadIdx.x;

    const int b = blockIdx.x >> 10;     // 1024 blocks per image (uniform per block)
    const int p = idx & (HW - 1);
    const int y = p >> 9;
    const int x = p & (WID - 1);

    // SRD for this batch's image: OOB rows fall outside num_records -> 0.
    union {
        struct { const void* base; unsigned num; unsigned cfg; } s;
        int32x4 v;
    } desc;
    desc.s.base = (const void*)(input + (size_t)b * HW);
    desc.s.num  = HW * 4u;
    desc.s.cfg  = 0x00020000u;
    const int32x4 rsrc = desc.v;

    // ---- per-pixel matrix (exactly mirrors numpy op order; amplified path) ----
    const size_t l_off = (size_t)idx * 3;
    const float L0 = Lp[l_off + 0];
    const float L1 = Lp[l_off + 1];
    const float L2 = Lp[l_off + 2];

    const float a  = fabsf(L0) + EPS_L;
    const float bb = L1;
    const float c  = fabsf(L2) + EPS_L;

    const float M00 = a * a;
    const float M01 = a * bb;
    const float M11 = (bb * bb) + (c * c);

    const float d00 = M00 + EPS;
    const float d11 = M11 + EPS;
    const float det = (d00 * d11) - (M01 * M01);
    const float I00 = d11 / det;          // IEEE f32 div, same as np
    const float I01 = (-M01) / det;
    const float I11 = d00 / det;

    const float wx = wbuf[(size_t)b * 2 * HW + p];
    const float wy = wbuf[(size_t)b * 2 * HW + HW + p];

    const float q    = (((I00 * wx) * wx) + (((2.0f * I01) * wx) * wy)) + ((I11 * wy) * wy);
    const float norm = sqrtf(q + EPS);

    const float e    = (float)exp((double)(-norm));   // correctly-rounded f32 exp
    const float sig  = 1.0f / (1.0f + e);
    const float tuned = ((sig - 0.5f) * 2.0f) * (1.0f - EPS_W);
    const float scale = tuned / (norm + EPS);         // IEEE div
    const float wtx = wx * scale;
    const float wty = wy * scale;

    // cos/sin of the FLOAT32-ROUNDED theta_k
    const float CT[K_SIZE] = { 1.0f,  0.30901696090f, -0.80901703575f, -0.80901693229f,  0.30901712828f };
    const float ST[K_SIZE] = { 0.0f,  0.95105652717f,  0.58778519534f, -0.58778533774f, -0.95105647279f };
    const float SV[K_SIZE] = { 0.2f, 0.4f, 0.6f, 0.8f, 1.0f };

    const float fy = (float)y;
    const float fx = (float)x;

    float acc0 = 0.0f;
    float acc1 = 0.0f;

    #pragma unroll
    for (int k = 0; k < K_SIZE; ++k) {
        const float ct = CT[k];
        const float st = ST[k];
        // amplified path: keep exact left-assoc, no contraction
        const float quad = (((M00 * ct) * ct) + (((2.0f * M01) * ct) * st)) + ((M11 * st) * st);
        const float F    = (sqrtf(quad) + (wtx * ct)) + (wty * st);
        const float Fe   = F + EPS;
        // downstream of cancellation: approx rcp safe (position error ~1e-7 rel)
        const float rFe  = __builtin_amdgcn_rcpf(Fe);
        const float yx   = ct * rFe;
        const float yy   = st * rFe;

        // ---- phase 1: compute all 5 samples' coords, issue all 20 loads ----
        // (constant indices after unroll -> registers; ~20 loads in flight)
        float v00A[K_SIZE], v01A[K_SIZE], v10A[K_SIZE], v11A[K_SIZE];
        float wyfA[K_SIZE], zx0A[K_SIZE], zx1A[K_SIZE];

        #pragma unroll
        for (int s = 0; s < K_SIZE; ++s) {
            const float sv = SV[s];
            const float gy = fmaf(sv, yy, fy);
            const float gx = fmaf(sv, yx, fx);

            const int   y0i = (int)floorf(gy);      // v_cvt_flr_i32_f32
            const int   x0i = (int)floorf(gx);
            const float wyf = __builtin_amdgcn_fractf(gy);
            const float wxf = __builtin_amdgcn_fractf(gx);

            // y handled by HW bounds check: OOB row -> outside SRD -> 0.
            const unsigned r0 = (unsigned)y0i << 11;          // byte offset of row y0
            const unsigned r1 = r0 + (WID * 4u);              // row y0+1

            const int x1i = x0i + 1;
            const bool vx0 = (unsigned)x0i < (unsigned)WID;
            const bool vx1 = (unsigned)x1i < (unsigned)WID;
            const unsigned x0v = (unsigned)min(max(x0i, 0), WID - 1) << 2;
            const unsigned x1v = (unsigned)min(max(x1i, 0), WID - 1) << 2;

            v00A[s] = llvm_amdgcn_raw_buffer_load_fp32(rsrc, (int)(r0 + x0v), 0, 0);
            v01A[s] = llvm_amdgcn_raw_buffer_load_fp32(rsrc, (int)(r0 + x1v), 0, 0);
            v10A[s] = llvm_amdgcn_raw_buffer_load_fp32(rsrc, (int)(r1 + x0v), 0, 0);
            v11A[s] = llvm_amdgcn_raw_buffer_load_fp32(rsrc, (int)(r1 + x1v), 0, 0);

            wyfA[s] = wyf;
            zx0A[s] = vx0 ? (1.0f - wxf) : 0.0f;
            zx1A[s] = vx1 ? wxf : 0.0f;
        }

        // ---- phase 2: consume ----
        #pragma unroll
        for (int s = 0; s < K_SIZE; ++s) {
            const float row0 = fmaf(v01A[s], zx1A[s], v00A[s] * zx0A[s]);
            const float row1 = fmaf(v11A[s], zx1A[s], v10A[s] * zx0A[s]);
            if (s & 1) {
                acc1 = fmaf(1.0f - wyfA[s], row0, acc1);
                acc1 = fmaf(wyfA[s],        row1, acc1);
            } else {
                acc0 = fmaf(1.0f - wyfA[s], row0, acc0);
                acc0 = fmaf(wyfA[s],        row1, acc0);
            }
        }
    }

    out[idx] = (acc0 + acc1) / (float)(K_SIZE * K_SIZE);
}

extern "C" void kernel_launch(void* const* d_in, const int* in_sizes, int n_in,
                              void* d_out, int out_size, void* d_ws, size_t ws_size,
                              hipStream_t stream) {
    const float* input = (const float*)d_in[0];
    const float* Lp    = (const float*)d_in[1];
    const float* wbuf  = (const float*)d_in[2];
    float* out = (float*)d_out;

    const int total = BATCH * HW;            // 1,048,576
    const int block = 256;
    const int grid  = (total + block - 1) / block;   // 4096
    fused_sample_kernel<<<grid, block, 0, stream>>>(input, Lp, wbuf, out);
}

// Round 7
// 42.873 us; speedup vs baseline: 1.9979x; 1.2902x over previous
//
#include <hip/hip_runtime.h>
#include <math.h>

#define K_SIZE 5
#define EPS    1e-6f
#define EPS_L  1e-3f
#define EPS_W  1e-3f

#define BATCH 4
#define HGT   512
#define WID   512
#define HW    (HGT * WID)

// fp16 pair table layout: entry[b][y][k] (k = 0..512) = { img[y][k-1], img[y][k] }
// (invalid halves stored as 0). Row stride padded to 516 entries for alignment.
#define ROW_ENTRIES 516
#define ROW_BYTES   (ROW_ENTRIES * 4)          // 2064
#define IMG_BYTES   (HGT * ROW_BYTES)          // 1,056,768
#define TBL_BYTES   ((size_t)BATCH * IMG_BYTES)

typedef int int32x4 __attribute__((ext_vector_type(4)));
typedef _Float16 half2v __attribute__((ext_vector_type(2)));

// Raw buffer load with hardware bounds check: OOB -> returns 0.0f
__device__ float llvm_amdgcn_raw_buffer_load_fp32(int32x4 srsrc, int voffset,
                                                  int soffset, int aux)
    __asm("llvm.amdgcn.raw.buffer.load.f32");

// ---------------- pack: f32 image -> fp16 pair table ----------------
__global__ __launch_bounds__(256) void pack_kernel(
    const float* __restrict__ input, char* __restrict__ tbl)
{
    const int ENT = 513;
    const int t = blockIdx.x * blockDim.x + threadIdx.x;
    if (t >= BATCH * HGT * ENT) return;
    const int k  = t % ENT;
    const int yy = (t / ENT) % HGT;
    const int b  = t / (ENT * HGT);

    const float* __restrict__ img = input + (size_t)b * HW + (size_t)yy * WID;
    const float lo = (k >= 1)   ? img[k - 1] : 0.0f;   // x = k-1
    const float hi = (k <= 511) ? img[k]     : 0.0f;   // x = k
    union { half2v h; float f; } cv;
    cv.h.x = (_Float16)lo;
    cv.h.y = (_Float16)hi;
    float* dst = (float*)(tbl + (size_t)b * IMG_BYTES + (size_t)yy * ROW_BYTES) + k;
    *dst = cv.f;
}

// ---------------- main fused kernel (fp16 pair-table gather) ----------------
__global__ __launch_bounds__(256) void fused_sample_kernel_f16(
    const char* __restrict__ tbl,      // packed table in ws
    const float* __restrict__ Lp,      // (B,H,W,3)
    const float* __restrict__ wbuf,    // (B,2,H,W)
    float* __restrict__ out)           // (B,1,H,W)
{
#pragma clang fp contract(off)
    const int idx = blockIdx.x * blockDim.x + threadIdx.x;

    const int b = blockIdx.x >> 10;     // 1024 blocks per image (uniform per block)
    const int p = idx & (HW - 1);
    const int y = p >> 9;
    const int x = p & (WID - 1);

    // SRD over this image's table: OOB rows fall outside num_records -> 0.
    union {
        struct { const void* base; unsigned num; unsigned cfg; } s;
        int32x4 v;
    } desc;
    desc.s.base = (const void*)(tbl + (size_t)b * IMG_BYTES);
    desc.s.num  = (unsigned)IMG_BYTES;
    desc.s.cfg  = 0x00020000u;
    const int32x4 rsrc = desc.v;

    // ---- per-pixel matrix (exactly mirrors numpy op order; amplified path) ----
    const size_t l_off = (size_t)idx * 3;
    const float L0 = Lp[l_off + 0];
    const float L1 = Lp[l_off + 1];
    const float L2 = Lp[l_off + 2];

    const float a  = fabsf(L0) + EPS_L;
    const float bb = L1;
    const float c  = fabsf(L2) + EPS_L;

    const float M00 = a * a;
    const float M01 = a * bb;
    const float M11 = (bb * bb) + (c * c);

    const float d00 = M00 + EPS;
    const float d11 = M11 + EPS;
    const float det = (d00 * d11) - (M01 * M01);
    const float I00 = d11 / det;          // IEEE f32 div, same as np
    const float I01 = (-M01) / det;
    const float I11 = d00 / det;

    const float wx = wbuf[(size_t)b * 2 * HW + p];
    const float wy = wbuf[(size_t)b * 2 * HW + HW + p];

    const float q    = (((I00 * wx) * wx) + (((2.0f * I01) * wx) * wy)) + ((I11 * wy) * wy);
    const float norm = sqrtf(q + EPS);

    const float e    = (float)exp((double)(-norm));   // correctly-rounded f32 exp
    const float sig  = 1.0f / (1.0f + e);
    const float tuned = ((sig - 0.5f) * 2.0f) * (1.0f - EPS_W);
    const float scale = tuned / (norm + EPS);         // IEEE div
    const float wtx = wx * scale;
    const float wty = wy * scale;

    // cos/sin of the FLOAT32-ROUNDED theta_k
    const float CT[K_SIZE] = { 1.0f,  0.30901696090f, -0.80901703575f, -0.80901693229f,  0.30901712828f };
    const float ST[K_SIZE] = { 0.0f,  0.95105652717f,  0.58778519534f, -0.58778533774f, -0.95105647279f };
    const float SV[K_SIZE] = { 0.2f, 0.4f, 0.6f, 0.8f, 1.0f };

    const float fy = (float)y;
    const float fx = (float)x;

    float acc0 = 0.0f;
    float acc1 = 0.0f;

    #pragma unroll
    for (int k = 0; k < K_SIZE; ++k) {
        const float ct = CT[k];
        const float st = ST[k];
        // amplified path: keep exact left-assoc, no contraction
        const float quad = (((M00 * ct) * ct) + (((2.0f * M01) * ct) * st)) + ((M11 * st) * st);
        const float F    = (sqrtf(quad) + (wtx * ct)) + (wty * st);
        const float Fe   = F + EPS;
        // downstream of cancellation: approx rcp safe (position error ~1e-7 rel)
        const float rFe  = __builtin_amdgcn_rcpf(Fe);
        const float yx   = ct * rFe;
        const float yy   = st * rFe;

        #pragma unroll
        for (int s = 0; s < K_SIZE; ++s) {
            const float sv = SV[s];
            const float gy = fmaf(sv, yy, fy);
            const float gx = fmaf(sv, yx, fx);

            const int   y0i = (int)floorf(gy);      // v_cvt_flr_i32_f32
            const int   x0i = (int)floorf(gx);
            const float wyf = __builtin_amdgcn_fractf(gy);
            const float wxf = __builtin_amdgcn_fractf(gx);

            // entry index k = x0+1, clamped to the row's valid entries
            const int   ke  = min(max(x0i + 1, 0), 512);
            // row byte offsets; OOB y -> outside SRD -> 0. (For y0i == -1,
            // off1 wraps exactly to row 0 == correct row for y1=0.)
            const unsigned r0   = (unsigned)y0i * (unsigned)ROW_BYTES;
            const unsigned off0 = r0 + ((unsigned)ke << 2);
            const unsigned off1 = off0 + (unsigned)ROW_BYTES;

            const float p0f = llvm_amdgcn_raw_buffer_load_fp32(rsrc, (int)off0, 0, 0);
            const float p1f = llvm_amdgcn_raw_buffer_load_fp32(rsrc, (int)off1, 0, 0);

            union { float f; half2v h; } c0, c1;
            c0.f = p0f;
            c1.f = p1f;
            const float v00 = (float)c0.h.x;
            const float v01 = (float)c0.h.y;
            const float v10 = (float)c1.h.x;
            const float v11 = (float)c1.h.y;

            const int x1i = x0i + 1;
            const bool vx0 = (unsigned)x0i < (unsigned)WID;
            const bool vx1 = (unsigned)x1i < (unsigned)WID;
            const float zx0 = vx0 ? (1.0f - wxf) : 0.0f;
            const float zx1 = vx1 ? wxf : 0.0f;

            const float row0 = fmaf(v01, zx1, v00 * zx0);
            const float row1 = fmaf(v11, zx1, v10 * zx0);

            if (s & 1) {
                acc1 = fmaf(1.0f - wyf, row0, acc1);
                acc1 = fmaf(wyf,        row1, acc1);
            } else {
                acc0 = fmaf(1.0f - wyf, row0, acc0);
                acc0 = fmaf(wyf,        row1, acc0);
            }
        }
    }

    out[idx] = (acc0 + acc1) / (float)(K_SIZE * K_SIZE);
}

// ---------------- fallback: direct fp32 gather (proven, ~55us) ----------------
__global__ __launch_bounds__(256) void fused_sample_kernel_f32(
    const float* __restrict__ input,
    const float* __restrict__ Lp,
    const float* __restrict__ wbuf,
    float* __restrict__ out)
{
#pragma clang fp contract(off)
    const int idx = blockIdx.x * blockDim.x + threadIdx.x;
    const int b = blockIdx.x >> 10;
    const int p = idx & (HW - 1);
    const int y = p >> 9;
    const int x = p & (WID - 1);

    union {
        struct { const void* base; unsigned num; unsigned cfg; } s;
        int32x4 v;
    } desc;
    desc.s.base = (const void*)(input + (size_t)b * HW);
    desc.s.num  = HW * 4u;
    desc.s.cfg  = 0x00020000u;
    const int32x4 rsrc = desc.v;

    const size_t l_off = (size_t)idx * 3;
    const float L0 = Lp[l_off + 0];
    const float L1 = Lp[l_off + 1];
    const float L2 = Lp[l_off + 2];

    const float a  = fabsf(L0) + EPS_L;
    const float bb = L1;
    const float c  = fabsf(L2) + EPS_L;

    const float M00 = a * a;
    const float M01 = a * bb;
    const float M11 = (bb * bb) + (c * c);

    const float d00 = M00 + EPS;
    const float d11 = M11 + EPS;
    const float det = (d00 * d11) - (M01 * M01);
    const float I00 = d11 / det;
    const float I01 = (-M01) / det;
    const float I11 = d00 / det;

    const float wx = wbuf[(size_t)b * 2 * HW + p];
    const float wy = wbuf[(size_t)b * 2 * HW + HW + p];

    const float q    = (((I00 * wx) * wx) + (((2.0f * I01) * wx) * wy)) + ((I11 * wy) * wy);
    const float norm = sqrtf(q + EPS);
    const float e    = (float)exp((double)(-norm));
    const float sig  = 1.0f / (1.0f + e);
    const float tuned = ((sig - 0.5f) * 2.0f) * (1.0f - EPS_W);
    const float scale = tuned / (norm + EPS);
    const float wtx = wx * scale;
    const float wty = wy * scale;

    const float CT[K_SIZE] = { 1.0f,  0.30901696090f, -0.80901703575f, -0.80901693229f,  0.30901712828f };
    const float ST[K_SIZE] = { 0.0f,  0.95105652717f,  0.58778519534f, -0.58778533774f, -0.95105647279f };
    const float SV[K_SIZE] = { 0.2f, 0.4f, 0.6f, 0.8f, 1.0f };

    const float fy = (float)y;
    const float fx = (float)x;

    float acc0 = 0.0f;
    float acc1 = 0.0f;

    #pragma unroll
    for (int k = 0; k < K_SIZE; ++k) {
        const float ct = CT[k];
        const float st = ST[k];
        const float quad = (((M00 * ct) * ct) + (((2.0f * M01) * ct) * st)) + ((M11 * st) * st);
        const float F    = (sqrtf(quad) + (wtx * ct)) + (wty * st);
        const float Fe   = F + EPS;
        const float rFe  = __builtin_amdgcn_rcpf(Fe);
        const float yx   = ct * rFe;
        const float yy   = st * rFe;

        #pragma unroll
        for (int s = 0; s < K_SIZE; ++s) {
            const float sv = SV[s];
            const float gy = fmaf(sv, yy, fy);
            const float gx = fmaf(sv, yx, fx);

            const int   y0i = (int)floorf(gy);
            const int   x0i = (int)floorf(gx);
            const float wyf = __builtin_amdgcn_fractf(gy);
            const float wxf = __builtin_amdgcn_fractf(gx);

            const unsigned r0 = (unsigned)y0i << 11;
            const unsigned r1 = r0 + (WID * 4u);

            const int x1i = x0i + 1;
            const bool vx0 = (unsigned)x0i < (unsigned)WID;
            const bool vx1 = (unsigned)x1i < (unsigned)WID;
            const unsigned x0v = (unsigned)min(max(x0i, 0), WID - 1) << 2;
            const unsigned x1v = (unsigned)min(max(x1i, 0), WID - 1) << 2;

            const float v00 = llvm_amdgcn_raw_buffer_load_fp32(rsrc, (int)(r0 + x0v), 0, 0);
            const float v01 = llvm_amdgcn_raw_buffer_load_fp32(rsrc, (int)(r0 + x1v), 0, 0);
            const float v10 = llvm_amdgcn_raw_buffer_load_fp32(rsrc, (int)(r1 + x0v), 0, 0);
            const float v11 = llvm_amdgcn_raw_buffer_load_fp32(rsrc, (int)(r1 + x1v), 0, 0);

            const float zx0 = vx0 ? (1.0f - wxf) : 0.0f;
            const float zx1 = vx1 ? wxf : 0.0f;

            const float row0 = fmaf(v01, zx1, v00 * zx0);
            const float row1 = fmaf(v11, zx1, v10 * zx0);

            if (s & 1) {
                acc1 = fmaf(1.0f - wyf, row0, acc1);
                acc1 = fmaf(wyf,        row1, acc1);
            } else {
                acc0 = fmaf(1.0f - wyf, row0, acc0);
                acc0 = fmaf(wyf,        row1, acc0);
            }
        }
    }

    out[idx] = (acc0 + acc1) / (float)(K_SIZE * K_SIZE);
}

extern "C" void kernel_launch(void* const* d_in, const int* in_sizes, int n_in,
                              void* d_out, int out_size, void* d_ws, size_t ws_size,
                              hipStream_t stream) {
    const float* input = (const float*)d_in[0];
    const float* Lp    = (const float*)d_in[1];
    const float* wbuf  = (const float*)d_in[2];
    float* out = (float*)d_out;

    if (ws_size >= TBL_BYTES) {
        char* tbl = (char*)d_ws;
        const int pack_total = BATCH * HGT * 513;              // 1,050,624
        pack_kernel<<<(pack_total + 255) / 256, 256, 0, stream>>>(input, tbl);
        fused_sample_kernel_f16<<<BATCH * HW / 256, 256, 0, stream>>>(tbl, Lp, wbuf, out);
    } else {
        fused_sample_kernel_f32<<<BATCH * HW / 256, 256, 0, stream>>>(input, Lp, wbuf, out);
    }
}

// Round 8
// 39.858 us; speedup vs baseline: 2.1490x; 1.0756x over previous
//
#include <hip/hip_runtime.h>
#include <math.h>

#define K_SIZE 5
#define EPS    1e-6f
#define EPS_L  1e-3f
#define EPS_W  1e-3f

#define BATCH 4
#define HGT   512
#define WID   512
#define HW    (HGT * WID)

// fp16 quad table: entry[b][ri][k] (ri,k in 0..512) =
//   { img[ri-1][k-1], img[ri-1][k], img[ri][k-1], img[ri][k] }  (OOB halves = 0)
// ri = y0+1, k = x0+1. One 8B load -> all 4 bilinear corners.
#define ENT        513
#define ROW_ENTRIES 520                         // pad for 64B-aligned rows
#define ROW_BYTES  (ROW_ENTRIES * 8)            // 4160 = 64*65
#define IMG_BYTES  (ENT * ROW_BYTES)            // 2,134,080
#define TBL_BYTES  ((size_t)BATCH * IMG_BYTES)  // ~8.5 MB

typedef int int32x4 __attribute__((ext_vector_type(4)));
typedef float floatx2 __attribute__((ext_vector_type(2)));
typedef _Float16 half4v __attribute__((ext_vector_type(4)));
typedef _Float16 half2v __attribute__((ext_vector_type(2)));

// Raw buffer loads with hardware bounds check: OOB -> returns 0
__device__ float llvm_amdgcn_raw_buffer_load_fp32(int32x4 srsrc, int voffset,
                                                  int soffset, int aux)
    __asm("llvm.amdgcn.raw.buffer.load.f32");
__device__ floatx2 llvm_amdgcn_raw_buffer_load_2fp32(int32x4 srsrc, int voffset,
                                                     int soffset, int aux)
    __asm("llvm.amdgcn.raw.buffer.load.v2f32");

// ---------------- pack: f32 image -> fp16 quad table ----------------
__global__ __launch_bounds__(256) void pack_kernel(
    const float* __restrict__ input, char* __restrict__ tbl)
{
    const int t = blockIdx.x * blockDim.x + threadIdx.x;
    if (t >= BATCH * ENT * ENT) return;
    const int k  = t % ENT;
    const int ri = (t / ENT) % ENT;
    const int b  = t / (ENT * ENT);

    const float* __restrict__ img = input + (size_t)b * HW;

    const bool top = (ri >= 1), bot = (ri <= HGT - 1);
    const bool lef = (k  >= 1), rig = (k  <= WID - 1);
    const int yT = (ri - 1) << 9;
    const int yB = ri << 9;

    union { half4v h; floatx2 f; } cv;
    cv.h.x = (_Float16)((top && lef) ? img[yT + k - 1] : 0.0f);
    cv.h.y = (_Float16)((top && rig) ? img[yT + k]     : 0.0f);
    cv.h.z = (_Float16)((bot && lef) ? img[yB + k - 1] : 0.0f);
    cv.h.w = (_Float16)((bot && rig) ? img[yB + k]     : 0.0f);

    floatx2* dst = (floatx2*)(tbl + (size_t)b * IMG_BYTES + (size_t)ri * ROW_BYTES + ((size_t)k << 3));
    *dst = cv.f;
}

// ---------------- main fused kernel (fp16 quad-table gather) ----------------
__global__ __launch_bounds__(256) void fused_sample_kernel_f16(
    const char* __restrict__ tbl,      // packed table in ws
    const float* __restrict__ Lp,      // (B,H,W,3)
    const float* __restrict__ wbuf,    // (B,2,H,W)
    float* __restrict__ out)           // (B,1,H,W)
{
#pragma clang fp contract(off)
    const int idx = blockIdx.x * blockDim.x + threadIdx.x;

    const int b = blockIdx.x >> 10;     // 1024 blocks per image (uniform per block)
    const int p = idx & (HW - 1);
    const int y = p >> 9;
    const int x = p & (WID - 1);

    // SRD over this image's table: OOB rows -> outside num_records -> 0.
    union {
        struct { const void* base; unsigned num; unsigned cfg; } s;
        int32x4 v;
    } desc;
    desc.s.base = (const void*)(tbl + (size_t)b * IMG_BYTES);
    desc.s.num  = (unsigned)IMG_BYTES;
    desc.s.cfg  = 0x00020000u;
    const int32x4 rsrc = desc.v;

    // ---- per-pixel matrix (exactly mirrors numpy op order; amplified path) ----
    const size_t l_off = (size_t)idx * 3;
    const float L0 = Lp[l_off + 0];
    const float L1 = Lp[l_off + 1];
    const float L2 = Lp[l_off + 2];

    const float a  = fabsf(L0) + EPS_L;
    const float bb = L1;
    const float c  = fabsf(L2) + EPS_L;

    const float M00 = a * a;
    const float M01 = a * bb;
    const float M11 = (bb * bb) + (c * c);

    const float d00 = M00 + EPS;
    const float d11 = M11 + EPS;
    const float det = (d00 * d11) - (M01 * M01);
    const float I00 = d11 / det;          // IEEE f32 div, same as np
    const float I01 = (-M01) / det;
    const float I11 = d00 / det;

    const float wx = wbuf[(size_t)b * 2 * HW + p];
    const float wy = wbuf[(size_t)b * 2 * HW + HW + p];

    const float q    = (((I00 * wx) * wx) + (((2.0f * I01) * wx) * wy)) + ((I11 * wy) * wy);
    const float norm = sqrtf(q + EPS);

    const float e    = (float)exp((double)(-norm));   // correctly-rounded f32 exp
    const float sig  = 1.0f / (1.0f + e);
    const float tuned = ((sig - 0.5f) * 2.0f) * (1.0f - EPS_W);
    const float scale = tuned / (norm + EPS);         // IEEE div
    const float wtx = wx * scale;
    const float wty = wy * scale;

    // cos/sin of the FLOAT32-ROUNDED theta_k
    const float CT[K_SIZE] = { 1.0f,  0.30901696090f, -0.80901703575f, -0.80901693229f,  0.30901712828f };
    const float ST[K_SIZE] = { 0.0f,  0.95105652717f,  0.58778519534f, -0.58778533774f, -0.95105647279f };
    const float SV[K_SIZE] = { 0.2f, 0.4f, 0.6f, 0.8f, 1.0f };

    const float fy = (float)y;
    const float fx = (float)x;

    float acc0 = 0.0f;
    float acc1 = 0.0f;

    #pragma unroll
    for (int k = 0; k < K_SIZE; ++k) {
        const float ct = CT[k];
        const float st = ST[k];
        // amplified path: keep exact left-assoc, no contraction
        const float quad = (((M00 * ct) * ct) + (((2.0f * M01) * ct) * st)) + ((M11 * st) * st);
        const float F    = (sqrtf(quad) + (wtx * ct)) + (wty * st);
        const float Fe   = F + EPS;
        // downstream of cancellation: approx rcp safe (position error ~1e-7 rel)
        const float rFe  = __builtin_amdgcn_rcpf(Fe);
        const float yx   = ct * rFe;
        const float yy   = st * rFe;

        #pragma unroll
        for (int s = 0; s < K_SIZE; ++s) {
            const float sv = SV[s];
            const float gy = fmaf(sv, yy, fy);
            const float gx = fmaf(sv, yx, fx);

            const int   y0i = (int)floorf(gy);      // v_cvt_flr_i32_f32
            const int   x0i = (int)floorf(gx);
            const float wyf = __builtin_amdgcn_fractf(gy);
            const float wxf = __builtin_amdgcn_fractf(gx);

            // quad-entry coords: ri = y0+1 (row OOB -> SRD returns 0),
            // ke = clamp(x0+1) with zero weights on clamped x.
            const int ri = y0i + 1;
            const int ke = min(max(x0i + 1, 0), ENT - 1);
            const unsigned off = (unsigned)ri * (unsigned)ROW_BYTES + ((unsigned)ke << 3);

            const floatx2 pf = llvm_amdgcn_raw_buffer_load_2fp32(rsrc, (int)off, 0, 0);
            union { floatx2 f; half4v h; } cv;
            cv.f = pf;
            const float v00 = (float)cv.h.x;
            const float v01 = (float)cv.h.y;
            const float v10 = (float)cv.h.z;
            const float v11 = (float)cv.h.w;

            const bool vx0 = (unsigned)x0i < (unsigned)WID;
            const bool vx1 = (unsigned)(x0i + 1) < (unsigned)WID;
            const float zx0 = vx0 ? (1.0f - wxf) : 0.0f;
            const float zx1 = vx1 ? wxf : 0.0f;

            const float row0 = fmaf(v01, zx1, v00 * zx0);
            const float row1 = fmaf(v11, zx1, v10 * zx0);

            if (s & 1) {
                acc1 = fmaf(1.0f - wyf, row0, acc1);
                acc1 = fmaf(wyf,        row1, acc1);
            } else {
                acc0 = fmaf(1.0f - wyf, row0, acc0);
                acc0 = fmaf(wyf,        row1, acc0);
            }
        }
    }

    out[idx] = (acc0 + acc1) / (float)(K_SIZE * K_SIZE);
}

// ---------------- fallback: direct fp32 gather (proven, ~55us) ----------------
__global__ __launch_bounds__(256) void fused_sample_kernel_f32(
    const float* __restrict__ input,
    const float* __restrict__ Lp,
    const float* __restrict__ wbuf,
    float* __restrict__ out)
{
#pragma clang fp contract(off)
    const int idx = blockIdx.x * blockDim.x + threadIdx.x;
    const int b = blockIdx.x >> 10;
    const int p = idx & (HW - 1);
    const int y = p >> 9;
    const int x = p & (WID - 1);

    union {
        struct { const void* base; unsigned num; unsigned cfg; } s;
        int32x4 v;
    } desc;
    desc.s.base = (const void*)(input + (size_t)b * HW);
    desc.s.num  = HW * 4u;
    desc.s.cfg  = 0x00020000u;
    const int32x4 rsrc = desc.v;

    const size_t l_off = (size_t)idx * 3;
    const float L0 = Lp[l_off + 0];
    const float L1 = Lp[l_off + 1];
    const float L2 = Lp[l_off + 2];

    const float a  = fabsf(L0) + EPS_L;
    const float bb = L1;
    const float c  = fabsf(L2) + EPS_L;

    const float M00 = a * a;
    const float M01 = a * bb;
    const float M11 = (bb * bb) + (c * c);

    const float d00 = M00 + EPS;
    const float d11 = M11 + EPS;
    const float det = (d00 * d11) - (M01 * M01);
    const float I00 = d11 / det;
    const float I01 = (-M01) / det;
    const float I11 = d00 / det;

    const float wx = wbuf[(size_t)b * 2 * HW + p];
    const float wy = wbuf[(size_t)b * 2 * HW + HW + p];

    const float q    = (((I00 * wx) * wx) + (((2.0f * I01) * wx) * wy)) + ((I11 * wy) * wy);
    const float norm = sqrtf(q + EPS);
    const float e    = (float)exp((double)(-norm));
    const float sig  = 1.0f / (1.0f + e);
    const float tuned = ((sig - 0.5f) * 2.0f) * (1.0f - EPS_W);
    const float scale = tuned / (norm + EPS);
    const float wtx = wx * scale;
    const float wty = wy * scale;

    const float CT[K_SIZE] = { 1.0f,  0.30901696090f, -0.80901703575f, -0.80901693229f,  0.30901712828f };
    const float ST[K_SIZE] = { 0.0f,  0.95105652717f,  0.58778519534f, -0.58778533774f, -0.95105647279f };
    const float SV[K_SIZE] = { 0.2f, 0.4f, 0.6f, 0.8f, 1.0f };

    const float fy = (float)y;
    const float fx = (float)x;

    float acc0 = 0.0f;
    float acc1 = 0.0f;

    #pragma unroll
    for (int k = 0; k < K_SIZE; ++k) {
        const float ct = CT[k];
        const float st = ST[k];
        const float quad = (((M00 * ct) * ct) + (((2.0f * M01) * ct) * st)) + ((M11 * st) * st);
        const float F    = (sqrtf(quad) + (wtx * ct)) + (wty * st);
        const float Fe   = F + EPS;
        const float rFe  = __builtin_amdgcn_rcpf(Fe);
        const float yx   = ct * rFe;
        const float yy   = st * rFe;

        #pragma unroll
        for (int s = 0; s < K_SIZE; ++s) {
            const float sv = SV[s];
            const float gy = fmaf(sv, yy, fy);
            const float gx = fmaf(sv, yx, fx);

            const int   y0i = (int)floorf(gy);
            const int   x0i = (int)floorf(gx);
            const float wyf = __builtin_amdgcn_fractf(gy);
            const float wxf = __builtin_amdgcn_fractf(gx);

            const unsigned r0 = (unsigned)y0i << 11;
            const unsigned r1 = r0 + (WID * 4u);

            const int x1i = x0i + 1;
            const bool vx0 = (unsigned)x0i < (unsigned)WID;
            const bool vx1 = (unsigned)x1i < (unsigned)WID;
            const unsigned x0v = (unsigned)min(max(x0i, 0), WID - 1) << 2;
            const unsigned x1v = (unsigned)min(max(x1i, 0), WID - 1) << 2;

            const float v00 = llvm_amdgcn_raw_buffer_load_fp32(rsrc, (int)(r0 + x0v), 0, 0);
            const float v01 = llvm_amdgcn_raw_buffer_load_fp32(rsrc, (int)(r0 + x1v), 0, 0);
            const float v10 = llvm_amdgcn_raw_buffer_load_fp32(rsrc, (int)(r1 + x0v), 0, 0);
            const float v11 = llvm_amdgcn_raw_buffer_load_fp32(rsrc, (int)(r1 + x1v), 0, 0);

            const float zx0 = vx0 ? (1.0f - wxf) : 0.0f;
            const float zx1 = vx1 ? wxf : 0.0f;

            const float row0 = fmaf(v01, zx1, v00 * zx0);
            const float row1 = fmaf(v11, zx1, v10 * zx0);

            if (s & 1) {
                acc1 = fmaf(1.0f - wyf, row0, acc1);
                acc1 = fmaf(wyf,        row1, acc1);
            } else {
                acc0 = fmaf(1.0f - wyf, row0, acc0);
                acc0 = fmaf(wyf,        row1, acc0);
            }
        }
    }

    out[idx] = (acc0 + acc1) / (float)(K_SIZE * K_SIZE);
}

extern "C" void kernel_launch(void* const* d_in, const int* in_sizes, int n_in,
                              void* d_out, int out_size, void* d_ws, size_t ws_size,
                              hipStream_t stream) {
    const float* input = (const float*)d_in[0];
    const float* Lp    = (const float*)d_in[1];
    const float* wbuf  = (const float*)d_in[2];
    float* out = (float*)d_out;

    if (ws_size >= TBL_BYTES) {
        char* tbl = (char*)d_ws;
        const int pack_total = BATCH * ENT * ENT;              // 1,052,676
        pack_kernel<<<(pack_total + 255) / 256, 256, 0, stream>>>(input, tbl);
        fused_sample_kernel_f16<<<BATCH * HW / 256, 256, 0, stream>>>(tbl, Lp, wbuf, out);
    } else {
        fused_sample_kernel_f32<<<BATCH * HW / 256, 256, 0, stream>>>(input, Lp, wbuf, out);
    }
}